// Round 6
// baseline (299.492 us; speedup 1.0000x reference)
//
#include <hip/hip_runtime.h>
#include <stdint.h>
#include <math.h>

#define HW   4096
#define NB   8
#define NC   512
#define C2   256
#define PT   32     // p-tile per block in argmax kernel
#define QC   256    // q-chunk per block

// ---------- ws layout (bytes) ----------
#define WS_PACKED 0         // u64 packed[8*4096]            = 262144
#define WS_INVN   262144    // f32 invn[8*4096]              = 131072
#define WS_Q0     393216    // i32 q0list[4096]              = 16384
#define WS_P1     409600    // i32 p1list[4096]              = 16384
#define WS_CNT    425984    // i32 cnt[2]
#define WS_IDX    427008    // i32 idx[8*4096]               = 131072

__device__ __forceinline__ unsigned long long mkkey(float v, unsigned q) {
    unsigned u = __float_as_uint(v);
    u = (u & 0x80000000u) ? ~u : (u | 0x80000000u);   // monotone float -> u32
    return ((unsigned long long)u << 32) | (unsigned long long)(0xFFFFFFFFu - q);
}

// --- 1. deterministic sorted compaction of flag into p1 (flag==1) / q0 (flag==0)
__global__ void compact_kernel(const int* __restrict__ flag, int* __restrict__ q0,
                               int* __restrict__ p1, int* __restrict__ cnt) {
    __shared__ int c1s[256];
    int t = threadIdx.x;
    int f[16]; int n1 = 0;
    #pragma unroll
    for (int j = 0; j < 16; ++j) { f[j] = flag[t*16 + j]; n1 += (f[j] == 1); }
    c1s[t] = n1;
    __syncthreads();
    if (t == 0) {
        int run = 0;
        for (int i = 0; i < 256; ++i) { int v = c1s[i]; c1s[i] = run; run += v; }
        cnt[0] = run;          // n1
        cnt[1] = HW - run;     // n0
    }
    __syncthreads();
    int b1 = c1s[t];
    int b0 = t*16 - c1s[t];
    for (int j = 0; j < 16; ++j) {
        int i = t*16 + j;
        if (f[j] == 1) p1[b1++] = i; else q0[b0++] = i;
    }
}

// --- 2. inv norms of latter columns
__global__ void norm_kernel(const float* __restrict__ x, float* __restrict__ invn) {
    int b = blockIdx.y;
    int q = blockIdx.x * 256 + threadIdx.x;
    const float* lf = x + ((size_t)b * NC + C2) * HW + q;
    float s = 0.f;
    #pragma unroll 8
    for (int c = 0; c < C2; ++c) {
        float v = lf[c * HW];
        s = fmaf(v, v, s);
    }
    invn[b * HW + q] = 1.0f / fmaxf(sqrtf(s), 1e-8f);
}

// --- 3. cos + argmax over unmasked q, merged via packed atomicMax
//     grid: (HW/PT tiles, 16 q-chunks of QC=256, NB); dead blocks exit.
//     j-loop = 4 (acc[8][4] = 32 regs) to land total VGPR <= 64: at 68
//     VGPRs (R5) waves/SIMD cap halves to 4 -> 29% occupancy. 12 live
//     blocks/CU (3072 total) hide gather latency via TLP.
//     ff staged in TWO c-halves of 128 (16.5 KB LDS, not binding).
//     NOTE: no min-waves clamp in launch_bounds — (256,4) forced VGPR=64
//     and spilled acc to scratch (13 GB HBM, 7x regression in R3).
__global__ void __launch_bounds__(256) argmax_kernel(
        const float* __restrict__ x, const float* __restrict__ invn,
        const int* __restrict__ q0, const int* __restrict__ p1,
        const int* __restrict__ cnt, unsigned long long* __restrict__ packed) {
    int tile  = blockIdx.x;
    int chunk = blockIdx.y;
    int b     = blockIdx.z;
    int n1 = cnt[0], n0 = cnt[1];
    if (tile * PT >= n1) return;
    if (chunk * QC >= n0) return;

    __shared__ float sff[128][PT];   // ff half-tile: [c][p] 16 KB
    __shared__ int   sp[PT];

    int t = threadIdx.x;
    if (t < PT) sp[t] = (tile * PT + t < n1) ? p1[tile * PT + t] : -1;

    const float* xb = x + (size_t)b * NC * HW;

    int tp = t >> 6;   // wave id -> 8-p sub-tile
    int tq = t & 63;   // lane    -> q
    const float* lfb = xb + C2 * HW;

    int voff[4];       // q indices (element offsets into a row)
    #pragma unroll
    for (int j = 0; j < 4; ++j) {
        int qi = chunk * QC + (j << 6) + tq;
        voff[j] = (qi < n0) ? q0[qi] : 0;
    }

    float acc[8][4];
    #pragma unroll
    for (int pi = 0; pi < 8; ++pi)
        #pragma unroll
        for (int j = 0; j < 4; ++j) acc[pi][j] = 0.f;

    const float* row = lfb;
    float bv[4];
    #pragma unroll
    for (int j = 0; j < 4; ++j) bv[j] = row[voff[j]];

    for (int h = 0; h < 2; ++h) {
        __syncthreads();   // h=0: sp visible; h=1: all waves done reading sff
        #pragma unroll 4
        for (int k = 0; k < 16; ++k) {      // 4096 elems / 256 threads
            int i = t + (k << 8);
            int c = i >> 5, j = i & 31;
            int p = sp[j];
            sff[c][j] = (p >= 0) ? xb[(h * 128 + c) * HW + p] : 0.f;
        }
        __syncthreads();

        #pragma unroll 2
        for (int cc = 0; cc < 128; ++cc) {
            int cglob = h * 128 + cc;
            // prefetch next c-row's gathers (clamped at last row)
            const float* prow = (cglob < 255) ? (row + HW) : row;
            float bvn[4];
            #pragma unroll
            for (int j = 0; j < 4; ++j) bvn[j] = prow[voff[j]];
            const float4* arow = (const float4*)&sff[cc][tp * 8];
            float4 a0 = arow[0], a1 = arow[1];
            float av[8] = {a0.x, a0.y, a0.z, a0.w, a1.x, a1.y, a1.z, a1.w};
            #pragma unroll
            for (int pi = 0; pi < 8; ++pi)
                #pragma unroll
                for (int j = 0; j < 4; ++j)
                    acc[pi][j] = fmaf(av[pi], bv[j], acc[pi][j]);
            #pragma unroll
            for (int j = 0; j < 4; ++j) bv[j] = bvn[j];
            row = prow;
        }
    }

    float best[8];
    int   bq[8];
    #pragma unroll
    for (int pi = 0; pi < 8; ++pi) { best[pi] = -INFINITY; bq[pi] = 0x7FFFFFFF; }

    #pragma unroll
    for (int j = 0; j < 4; ++j) {
        int qi = chunk * QC + (j << 6) + tq;
        if (qi >= n0) continue;
        float sc = invn[b * HW + voff[j]];
        #pragma unroll
        for (int pi = 0; pi < 8; ++pi) {
            float cv = acc[pi][j] * sc;
            if (cv > best[pi] || (cv == best[pi] && voff[j] < bq[pi])) {
                best[pi] = cv; bq[pi] = voff[j];
            }
        }
    }

    // wave reduce (all 64 lanes share the same 8 p's)
    #pragma unroll
    for (int m = 1; m < 64; m <<= 1) {
        #pragma unroll
        for (int pi = 0; pi < 8; ++pi) {
            float ov = __shfl_xor(best[pi], m);
            int   oq = __shfl_xor(bq[pi], m);
            if (ov > best[pi] || (ov == best[pi] && oq < bq[pi])) {
                best[pi] = ov; bq[pi] = oq;
            }
        }
    }
    if (tq == 0) {
        #pragma unroll
        for (int pi = 0; pi < 8; ++pi) {
            int pidx = tile * PT + tp * 8 + pi;
            int p = (pidx < n1) ? p1[pidx] : -1;
            if (p >= 0)
                atomicMax(&packed[(size_t)b * HW + p], mkkey(best[pi], (unsigned)bq[pi]));
        }
    }
}

// --- 4. decode packed keys -> idx
__global__ void decode_kernel(const unsigned long long* __restrict__ packed,
                              const int* __restrict__ flag, int* __restrict__ idx) {
    int b = blockIdx.y, p = blockIdx.x * 256 + threadIdx.x;
    int q = 0;
    if (flag[p] == 1) {
        unsigned low = (unsigned)(packed[(size_t)b * HW + p] & 0xFFFFFFFFull);
        q = (int)((0xFFFFFFFFu - low) & (HW - 1));
    }
    idx[b * HW + p] = q;
}

// --- 5. copy former+latter -> out channels [0,512)
__global__ void copy_kernel(const float4* __restrict__ x4, float4* __restrict__ out4) {
    size_t i = (size_t)blockIdx.x * 256 + threadIdx.x;
    if (i >= (size_t)NB * NC * (HW / 4)) return;
    size_t p4 = i & 1023;
    size_t c  = (i >> 10) & 511;
    size_t b  = i >> 19;
    out4[(b * 768 + c) * 1024 + p4] = x4[i];
}

// --- 6. shift writeback: out[b, 512+c, p] = flag[p] ? lf[b, c, idx[b,p]] : 0
__global__ void shift_kernel(const float* __restrict__ x, const int* __restrict__ flag,
                             const int* __restrict__ idx, float* __restrict__ out) {
    int cc = blockIdx.x, b = blockIdx.y;
    const float* lfrow = x + ((size_t)b * NC + C2 + cc) * HW;
    float*       orow  = out + ((size_t)b * 768 + 512 + cc) * HW;
    const int*   idxb  = idx + b * HW;
    for (int p = threadIdx.x; p < HW; p += 256) {
        float v = 0.f;
        if (flag[p] == 1) v = lfrow[idxb[p]];
        orow[p] = v;
    }
}

extern "C" void kernel_launch(void* const* d_in, const int* in_sizes, int n_in,
                              void* d_out, int out_size, void* d_ws, size_t ws_size,
                              hipStream_t stream) {
    const float* x    = (const float*)d_in[0];
    const int*   flag = (const int*)d_in[1];
    float*       out  = (float*)d_out;
    char*        ws   = (char*)d_ws;

    unsigned long long* packed = (unsigned long long*)(ws + WS_PACKED);
    float* invn = (float*)(ws + WS_INVN);
    int*   q0   = (int*)(ws + WS_Q0);
    int*   p1   = (int*)(ws + WS_P1);
    int*   cnt  = (int*)(ws + WS_CNT);
    int*   idx  = (int*)(ws + WS_IDX);

    hipMemsetAsync(packed, 0, (size_t)NB * HW * sizeof(unsigned long long), stream);

    compact_kernel<<<1, 256, 0, stream>>>(flag, q0, p1, cnt);
    norm_kernel<<<dim3(HW / 256, NB), 256, 0, stream>>>(x, invn);
    copy_kernel<<<(NB * NC * (HW / 4) + 255) / 256, 256, 0, stream>>>((const float4*)x, (float4*)out);
    argmax_kernel<<<dim3(HW / PT, HW / QC, NB), 256, 0, stream>>>(x, invn, q0, p1, cnt, packed);
    decode_kernel<<<dim3(HW / 256, NB), 256, 0, stream>>>(packed, flag, idx);
    shift_kernel<<<dim3(C2, NB), 256, 0, stream>>>(x, flag, idx, out);
}

// Round 7
// 287.960 us; speedup vs baseline: 1.0400x; 1.0400x over previous
//
#include <hip/hip_runtime.h>
#include <stdint.h>
#include <math.h>

#define HW   4096
#define NB   8
#define NC   512
#define C2   256
#define PT   32     // p-tile per block in argmax kernel
#define QC   512    // q-chunk per block (8 k per lane via two float4)

// ---------- ws layout (bytes) ----------
#define WS_PACKED 0         // u64 packed[8*4096]            = 262144
#define WS_INVN   262144    // f32 invn[8*4096]              = 131072
#define WS_Q0     393216    // i32 q0list[4096]              = 16384
#define WS_P1     409600    // i32 p1list[4096]              = 16384
#define WS_CNT    425984    // i32 cnt[2]
#define WS_IDX    427008    // i32 idx[8*4096]               = 131072
#define WS_INVC   558080    // f32 invc[8*4096]              = 131072
// total ~689 KB

__device__ __forceinline__ unsigned long long mkkey(float v, unsigned q) {
    unsigned u = __float_as_uint(v);
    u = (u & 0x80000000u) ? ~u : (u | 0x80000000u);   // monotone float -> u32
    return ((unsigned long long)u << 32) | (unsigned long long)(0xFFFFFFFFu - q);
}

// lfc scratch lives in d_out's shift region (channels [512,768) of batch b):
// 1M floats per batch, we need 256*ns <= 1M. Written by pack_kernel, read by
// argmax_kernel, then overwritten by shift_kernel at the end. No extra ws.
__device__ __forceinline__ float* lfc_region(float* out, int b) {
    return out + ((size_t)b * 768 + 512) * HW;
}

// --- 1. deterministic sorted compaction of flag into p1 (flag==1) / q0 (flag==0)
__global__ void compact_kernel(const int* __restrict__ flag, int* __restrict__ q0,
                               int* __restrict__ p1, int* __restrict__ cnt) {
    __shared__ int c1s[256];
    int t = threadIdx.x;
    int f[16]; int n1 = 0;
    #pragma unroll
    for (int j = 0; j < 16; ++j) { f[j] = flag[t*16 + j]; n1 += (f[j] == 1); }
    c1s[t] = n1;
    __syncthreads();
    if (t == 0) {
        int run = 0;
        for (int i = 0; i < 256; ++i) { int v = c1s[i]; c1s[i] = run; run += v; }
        cnt[0] = run;          // n1
        cnt[1] = HW - run;     // n0
    }
    __syncthreads();
    int b1 = c1s[t];
    int b0 = t*16 - c1s[t];
    for (int j = 0; j < 16; ++j) {
        int i = t*16 + j;
        if (f[j] == 1) p1[b1++] = i; else q0[b0++] = i;
    }
}

// --- 2. inv norms of latter columns
__global__ void norm_kernel(const float* __restrict__ x, float* __restrict__ invn) {
    int b = blockIdx.y;
    int q = blockIdx.x * 256 + threadIdx.x;
    const float* lf = x + ((size_t)b * NC + C2) * HW + q;
    float s = 0.f;
    #pragma unroll 8
    for (int c = 0; c < C2; ++c) {
        float v = lf[c * HW];
        s = fmaf(v, v, s);
    }
    invn[b * HW + q] = 1.0f / fmaxf(sqrtf(s), 1e-8f);
}

// --- 2b. pack: lfc[b][c][k] = lf[b][c][q0[k]], invc[b][k] = invn[b][q0[k]]
//     Converts the argmax inner-loop random gather into coalesced streams.
__global__ void pack_kernel(const float* __restrict__ x, const float* __restrict__ invn,
                            const int* __restrict__ q0, const int* __restrict__ cnt,
                            float* __restrict__ out, float* __restrict__ invc) {
    int b = blockIdx.z, c = blockIdx.y;
    int n0 = cnt[1];
    int ns = (n0 + 3) & ~3;                  // float4-aligned row stride
    int k = blockIdx.x * 256 + threadIdx.x;
    if (k >= n0) return;
    int q = q0[k];
    float* lfc = lfc_region(out, b);
    lfc[(size_t)c * ns + k] = x[((size_t)b * NC + C2 + c) * HW + q];
    if (c == 0) invc[b * HW + k] = invn[b * HW + q];
}

// --- 3. cos + argmax over unmasked q, merged via packed atomicMax
//     grid: (HW/PT tiles, 8 q-chunks of QC=512, NB); dead blocks exit.
//     Inner loop: per c, two coalesced global_load_dwordx4 from lfc
//     (L2-resident, linear addresses) + 2 LDS b128 broadcasts + 64 FMA.
//     NOTE: no min-waves clamp in launch_bounds — (256,4) forced VGPR=64
//     and spilled acc to scratch (13 GB HBM, 7x regression in R3).
__global__ void __launch_bounds__(256) argmax_kernel(
        const float* __restrict__ x, float* __restrict__ out,
        const float* __restrict__ invc,
        const int* __restrict__ q0, const int* __restrict__ p1,
        const int* __restrict__ cnt, unsigned long long* __restrict__ packed) {
    int tile  = blockIdx.x;
    int chunk = blockIdx.y;
    int b     = blockIdx.z;
    int n1 = cnt[0], n0 = cnt[1];
    if (tile * PT >= n1) return;
    if (chunk * QC >= n0) return;
    int ns = (n0 + 3) & ~3;

    __shared__ float sff[256][PT];   // ff tile: [c][p] 32 KB
    __shared__ int   sp[PT];

    int t = threadIdx.x;
    if (t < PT) sp[t] = (tile * PT + t < n1) ? p1[tile * PT + t] : -1;
    __syncthreads();

    const float* xb = x + (size_t)b * NC * HW;
    #pragma unroll
    for (int k = 0; k < 32; ++k) {      // 8192 elems / 256 threads
        int i = t + (k << 8);
        int c = i >> 5, j = i & 31;
        int p = sp[j];
        sff[c][j] = (p >= 0) ? xb[c * HW + p] : 0.f;
    }
    __syncthreads();

    int tp = t >> 6;   // wave id -> 8-p sub-tile
    int tq = t & 63;   // lane    -> k group
    const float* lfc = lfc_region(out, b);
    int kbase = chunk * QC + tq * 4;   // 16B aligned

    const float* r = lfc + kbase;      // advances by ns per c
    float4 bv0 = *(const float4*)(r);
    float4 bv1 = *(const float4*)(r + 256);
    r += ns;

    float acc[8][8];                   // [pi][j]: j 0-3 <- bv0, 4-7 <- bv1
    #pragma unroll
    for (int pi = 0; pi < 8; ++pi)
        #pragma unroll
        for (int j = 0; j < 8; ++j) acc[pi][j] = 0.f;

    #pragma unroll 2
    for (int c = 0; c < 255; ++c) {
        float4 nb0 = *(const float4*)(r);
        float4 nb1 = *(const float4*)(r + 256);
        r += ns;
        const float4* arow = (const float4*)&sff[c][tp * 8];
        float4 a0 = arow[0], a1 = arow[1];
        float av[8] = {a0.x, a0.y, a0.z, a0.w, a1.x, a1.y, a1.z, a1.w};
        float bv[8] = {bv0.x, bv0.y, bv0.z, bv0.w, bv1.x, bv1.y, bv1.z, bv1.w};
        #pragma unroll
        for (int pi = 0; pi < 8; ++pi)
            #pragma unroll
            for (int j = 0; j < 8; ++j)
                acc[pi][j] = fmaf(av[pi], bv[j], acc[pi][j]);
        bv0 = nb0; bv1 = nb1;
    }
    {   // c = 255 (no prefetch)
        const float4* arow = (const float4*)&sff[255][tp * 8];
        float4 a0 = arow[0], a1 = arow[1];
        float av[8] = {a0.x, a0.y, a0.z, a0.w, a1.x, a1.y, a1.z, a1.w};
        float bv[8] = {bv0.x, bv0.y, bv0.z, bv0.w, bv1.x, bv1.y, bv1.z, bv1.w};
        #pragma unroll
        for (int pi = 0; pi < 8; ++pi)
            #pragma unroll
            for (int j = 0; j < 8; ++j)
                acc[pi][j] = fmaf(av[pi], bv[j], acc[pi][j]);
    }

    float best[8];
    int   bq[8];
    #pragma unroll
    for (int pi = 0; pi < 8; ++pi) { best[pi] = -INFINITY; bq[pi] = 0x7FFFFFFF; }

    #pragma unroll
    for (int j = 0; j < 8; ++j) {
        int k = kbase + ((j < 4) ? j : 256 + (j - 4));
        if (k >= n0) continue;
        float sc = invc[b * HW + k];
        int   q  = q0[k];
        #pragma unroll
        for (int pi = 0; pi < 8; ++pi) {
            float cv = acc[pi][j] * sc;
            if (cv > best[pi] || (cv == best[pi] && q < bq[pi])) {
                best[pi] = cv; bq[pi] = q;
            }
        }
    }

    // wave reduce (all 64 lanes share the same 8 p's)
    #pragma unroll
    for (int m = 1; m < 64; m <<= 1) {
        #pragma unroll
        for (int pi = 0; pi < 8; ++pi) {
            float ov = __shfl_xor(best[pi], m);
            int   oq = __shfl_xor(bq[pi], m);
            if (ov > best[pi] || (ov == best[pi] && oq < bq[pi])) {
                best[pi] = ov; bq[pi] = oq;
            }
        }
    }
    if (tq == 0) {
        #pragma unroll
        for (int pi = 0; pi < 8; ++pi) {
            int pidx = tile * PT + tp * 8 + pi;
            int p = (pidx < n1) ? p1[pidx] : -1;
            if (p >= 0)
                atomicMax(&packed[(size_t)b * HW + p], mkkey(best[pi], (unsigned)bq[pi]));
        }
    }
}

// --- 4. decode packed keys -> idx
__global__ void decode_kernel(const unsigned long long* __restrict__ packed,
                              const int* __restrict__ flag, int* __restrict__ idx) {
    int b = blockIdx.y, p = blockIdx.x * 256 + threadIdx.x;
    int q = 0;
    if (flag[p] == 1) {
        unsigned low = (unsigned)(packed[(size_t)b * HW + p] & 0xFFFFFFFFull);
        q = (int)((0xFFFFFFFFu - low) & (HW - 1));
    }
    idx[b * HW + p] = q;
}

// --- 5. copy former+latter -> out channels [0,512)
__global__ void copy_kernel(const float4* __restrict__ x4, float4* __restrict__ out4) {
    size_t i = (size_t)blockIdx.x * 256 + threadIdx.x;
    if (i >= (size_t)NB * NC * (HW / 4)) return;
    size_t p4 = i & 1023;
    size_t c  = (i >> 10) & 511;
    size_t b  = i >> 19;
    out4[(b * 768 + c) * 1024 + p4] = x4[i];
}

// --- 6. shift writeback: out[b, 512+c, p] = flag[p] ? lf[b, c, idx[b,p]] : 0
//     (this overwrites the lfc scratch region — must run after argmax)
__global__ void shift_kernel(const float* __restrict__ x, const int* __restrict__ flag,
                             const int* __restrict__ idx, float* __restrict__ out) {
    int cc = blockIdx.x, b = blockIdx.y;
    const float* lfrow = x + ((size_t)b * NC + C2 + cc) * HW;
    float*       orow  = out + ((size_t)b * 768 + 512 + cc) * HW;
    const int*   idxb  = idx + b * HW;
    for (int p = threadIdx.x; p < HW; p += 256) {
        float v = 0.f;
        if (flag[p] == 1) v = lfrow[idxb[p]];
        orow[p] = v;
    }
}

extern "C" void kernel_launch(void* const* d_in, const int* in_sizes, int n_in,
                              void* d_out, int out_size, void* d_ws, size_t ws_size,
                              hipStream_t stream) {
    const float* x    = (const float*)d_in[0];
    const int*   flag = (const int*)d_in[1];
    float*       out  = (float*)d_out;
    char*        ws   = (char*)d_ws;

    unsigned long long* packed = (unsigned long long*)(ws + WS_PACKED);
    float* invn = (float*)(ws + WS_INVN);
    int*   q0   = (int*)(ws + WS_Q0);
    int*   p1   = (int*)(ws + WS_P1);
    int*   cnt  = (int*)(ws + WS_CNT);
    int*   idx  = (int*)(ws + WS_IDX);
    float* invc = (float*)(ws + WS_INVC);

    hipMemsetAsync(packed, 0, (size_t)NB * HW * sizeof(unsigned long long), stream);

    compact_kernel<<<1, 256, 0, stream>>>(flag, q0, p1, cnt);
    norm_kernel<<<dim3(HW / 256, NB), 256, 0, stream>>>(x, invn);
    pack_kernel<<<dim3(HW / 256, C2, NB), 256, 0, stream>>>(x, invn, q0, cnt, out, invc);
    copy_kernel<<<(NB * NC * (HW / 4) + 255) / 256, 256, 0, stream>>>((const float4*)x, (float4*)out);
    argmax_kernel<<<dim3(HW / PT, HW / QC, NB), 256, 0, stream>>>(x, out, invc, q0, p1, cnt, packed);
    decode_kernel<<<dim3(HW / 256, NB), 256, 0, stream>>>(packed, flag, idx);
    shift_kernel<<<dim3(C2, NB), 256, 0, stream>>>(x, flag, idx, out);
}